// Round 2
// baseline (1866.804 us; speedup 1.0000x reference)
//
#include <hip/hip_runtime.h>

typedef __attribute__((ext_vector_type(8))) short short8;
typedef __attribute__((ext_vector_type(4))) float f4;

__device__ __forceinline__ float b2f(unsigned short u) {
  union { unsigned int i; float f; } v; v.i = ((unsigned int)u) << 16; return v.f;
}
__device__ __forceinline__ unsigned short f2b(float f) {
  union { float f; unsigned int i; } v; v.f = f;
  unsigned int r = (v.i + 0x7FFFu + ((v.i >> 16) & 1u)) >> 16;
  return (unsigned short)r;
}

// WF32=true: p is float*, convert on load. WF32=false: p is bf16 bits (unsigned short*).
template<bool WF32>
__device__ __forceinline__ float ldv(const void* p, int i) {
  if constexpr (WF32) return ((const float*)p)[i];
  else return b2f(((const unsigned short*)p)[i]);
}

template<bool WF32>
__device__ __forceinline__ short8 ld8(const void* p, long idx) {
  short8 r;
  if constexpr (WF32) {
    const float4* f = (const float4*)((const float*)p + idx);
    float4 a = f[0], b = f[1];
    r[0] = (short)f2b(a.x); r[1] = (short)f2b(a.y);
    r[2] = (short)f2b(a.z); r[3] = (short)f2b(a.w);
    r[4] = (short)f2b(b.x); r[5] = (short)f2b(b.y);
    r[6] = (short)f2b(b.z); r[7] = (short)f2b(b.w);
  } else {
    r = *(const short8*)((const unsigned short*)p + idx);
  }
  return r;
}

// ---- one-shot weight f32->bf16 conversion into ws ----
#define OFF_PROJW 196608
#define OFF_QB    262144
#define OFF_VB    262400
#define OFF_PB    262656
#define OFF_LSC   262912
#define CONV_TOT  262920

__global__ void conv_kernel(const float* __restrict__ qkv_w, const float* __restrict__ proj_w,
                            const float* __restrict__ q_bias, const float* __restrict__ v_bias,
                            const float* __restrict__ proj_b, const float* __restrict__ lsc,
                            unsigned short* __restrict__ wbf) {
  int i = blockIdx.x * 256 + threadIdx.x;
  if (i >= CONV_TOT) return;
  float v;
  if (i < OFF_PROJW)      v = qkv_w[i];
  else if (i < OFF_QB)    v = proj_w[i - OFF_PROJW];
  else if (i < OFF_VB)    v = q_bias[i - OFF_QB];
  else if (i < OFF_PB)    v = v_bias[i - OFF_VB];
  else if (i < OFF_LSC)   v = proj_b[i - OFF_PB];
  else                    v = lsc[i - OFF_LSC];
  wbf[i] = f2b(v);
}

// ---- CPB MLP -> biasv[h][d] = 16*sigmoid(table[d][h]), d in [0,127) ----
__global__ void cpb_kernel(const float* __restrict__ w1, const float* __restrict__ b1,
                           const float* __restrict__ w2, float* __restrict__ biasv) {
  int p = blockIdx.x * 256 + threadIdx.x;
  if (p >= 127 * 8) return;
  int d = p >> 3, h = p & 7;
  float t = (float)(d - 63) * (8.0f / 63.0f);
  float sgn = (float)((t > 0.f) - (t < 0.f));
  float rc = sgn * log2f(fabsf(t) + 1.f) * (1.f / 3.f);
  float acc = 0.f;
  for (int j = 0; j < 512; ++j) {
    float hj = fmaxf(rc * w1[j] + b1[j], 0.f);
    acc += hj * w2[h * 512 + j];
  }
  biasv[h * 128 + d] = 16.f / (1.f + __expf(-acc));
}

// LDS strides (bf16 elems), 16B-aligned rows
#define QN_S 40
#define VT_S 72
#define PS_S 72

// 256 threads = 4 waves, one window per block.
// x strip lives in registers (af[8], 32 VGPR) -> no xs in LDS.
// Oh aliases into Ps cols 0..31 (PV reads of wave-private Ps rows precede Oh
// writes in program order; rows are wave-disjoint across waves).
// LDS: qn 5120 + kn 5120 + vt 4608 + Ps 9216 + bvs 4096 = 28160 B -> 3 blocks/CU.
// Barriers: 1 + 2 per head = 17, hidden by 2 other resident blocks.
template<bool WF32>
__launch_bounds__(256, 3)
__global__ void wattn_kernel(const float* __restrict__ x, const void* __restrict__ qkv_w,
                             const void* __restrict__ q_bias, const void* __restrict__ v_bias,
                             const void* __restrict__ lsc, const float* __restrict__ biasv,
                             const void* __restrict__ proj_w, const void* __restrict__ proj_b,
                             float* __restrict__ out) {
  __shared__ __align__(16) unsigned short qn[64 * QN_S];
  __shared__ __align__(16) unsigned short kn[64 * QN_S];
  __shared__ __align__(16) unsigned short vt[32 * VT_S];
  __shared__ __align__(16) unsigned short Ps[64 * PS_S];  // Oh aliased in cols 0..31
  __shared__ float bvs[8 * 128];

  const int tid = threadIdx.x;
  const int lane = tid & 63;
  const int wv = tid >> 6;      // 0..3, owns rows 16wv..16wv+15
  const int c = lane & 15;
  const int quad = lane >> 4;

  const long b = blockIdx.x;
  const long xbase = b * (64L * 256L);

  // A-fragments: this wave's 16-row x strip, f32->bf16, kept in registers for all heads.
  // row = 16wv + c, k = kt*32 + quad*8 (per-row 128B contiguous across quads -> coalesced)
  short8 af[8];
#pragma unroll
  for (int kt = 0; kt < 8; ++kt)
    af[kt] = ld8<true>(x, xbase + (long)(16 * wv + c) * 256 + kt * 32 + quad * 8);

  for (int i = tid; i < 1024; i += 256) bvs[i] = biasv[i];

  f4 accp[4][4];
#pragma unroll
  for (int i = 0; i < 4; ++i)
#pragma unroll
    for (int j = 0; j < 4; ++j) accp[i][j] = (f4){0.f, 0.f, 0.f, 0.f};

  __syncthreads();

  for (int h = 0; h < 8; ++h) {
    // ===== stage 1: QKV for this head; every wave computes its 16 rows x (q|k|v) =====
    {
      f4 acc[3][2];
#pragma unroll
      for (int p = 0; p < 3; ++p)
#pragma unroll
        for (int t = 0; t < 2; ++t) acc[p][t] = (f4){0.f, 0.f, 0.f, 0.f};

#pragma unroll
      for (int kt = 0; kt < 8; ++kt) {
        short8 bb[6];
#pragma unroll
        for (int p = 0; p < 3; ++p)
#pragma unroll
          for (int t = 0; t < 2; ++t)
            bb[p * 2 + t] = ld8<WF32>(qkv_w,
                (long)(p * 256 + h * 32 + 16 * t + c) * 256 + kt * 32 + quad * 8);
#pragma unroll
        for (int p = 0; p < 3; ++p)
#pragma unroll
          for (int t = 0; t < 2; ++t)
            acc[p][t] = __builtin_amdgcn_mfma_f32_16x16x32_bf16(af[kt], bb[p * 2 + t], acc[p][t], 0, 0, 0);
      }

      // writeback q (normalize)
      float qb0 = ldv<WF32>(q_bias, h * 32 + c);
      float qb1 = ldv<WF32>(q_bias, h * 32 + 16 + c);
#pragma unroll
      for (int r = 0; r < 4; ++r) {
        float v0 = acc[0][0][r] + qb0;
        float v1 = acc[0][1][r] + qb1;
        float ss = v0 * v0 + v1 * v1;
        ss += __shfl_xor(ss, 1);
        ss += __shfl_xor(ss, 2);
        ss += __shfl_xor(ss, 4);
        ss += __shfl_xor(ss, 8);
        float ri = rsqrtf(ss);
        int m = 16 * wv + quad * 4 + r;
        qn[m * QN_S + c] = f2b(v0 * ri);
        qn[m * QN_S + 16 + c] = f2b(v1 * ri);
      }
      // writeback k (normalize, no bias)
#pragma unroll
      for (int r = 0; r < 4; ++r) {
        float v0 = acc[1][0][r];
        float v1 = acc[1][1][r];
        float ss = v0 * v0 + v1 * v1;
        ss += __shfl_xor(ss, 1);
        ss += __shfl_xor(ss, 2);
        ss += __shfl_xor(ss, 4);
        ss += __shfl_xor(ss, 8);
        float ri = rsqrtf(ss);
        int m = 16 * wv + quad * 4 + r;
        kn[m * QN_S + c] = f2b(v0 * ri);
        kn[m * QN_S + 16 + c] = f2b(v1 * ri);
      }
      // writeback v (transposed, +bias)
      float vb0 = ldv<WF32>(v_bias, h * 32 + c);
      float vb1 = ldv<WF32>(v_bias, h * 32 + 16 + c);
#pragma unroll
      for (int r = 0; r < 4; ++r) {
        int m = 16 * wv + quad * 4 + r;
        vt[c * VT_S + m] = f2b(acc[2][0][r] + vb0);
        vt[(16 + c) * VT_S + m] = f2b(acc[2][1][r] + vb1);
      }
    }
    __syncthreads();  // qn/kn/vt ready

    // ===== stage 2: attention (wave-private 16-row strip) =====
    {
      float scale = __expf(fminf(ldv<WF32>(lsc, h), 4.6051702f));

      f4 s[4];
#pragma unroll
      for (int nt = 0; nt < 4; ++nt) s[nt] = (f4){0.f, 0.f, 0.f, 0.f};
      short8 aq = *(const short8*)&qn[(16 * wv + c) * QN_S + quad * 8];
#pragma unroll
      for (int nt = 0; nt < 4; ++nt) {
        short8 bk = *(const short8*)&kn[(16 * nt + c) * QN_S + quad * 8];
        s[nt] = __builtin_amdgcn_mfma_f32_16x16x32_bf16(aq, bk, s[nt], 0, 0, 0);
      }

      const float* bvh = bvs + h * 128 + 63;
#pragma unroll
      for (int r = 0; r < 4; ++r) {
        int m = 16 * wv + quad * 4 + r;
        float l[4];
#pragma unroll
        for (int nt = 0; nt < 4; ++nt)
          l[nt] = s[nt][r] * scale + bvh[m - 16 * nt - c];
        float mx = fmaxf(fmaxf(l[0], l[1]), fmaxf(l[2], l[3]));
        mx = fmaxf(mx, __shfl_xor(mx, 1));
        mx = fmaxf(mx, __shfl_xor(mx, 2));
        mx = fmaxf(mx, __shfl_xor(mx, 4));
        mx = fmaxf(mx, __shfl_xor(mx, 8));
        float p[4];
        float sum = 0.f;
#pragma unroll
        for (int nt = 0; nt < 4; ++nt) { p[nt] = __expf(l[nt] - mx); sum += p[nt]; }
        sum += __shfl_xor(sum, 1);
        sum += __shfl_xor(sum, 2);
        sum += __shfl_xor(sum, 4);
        sum += __shfl_xor(sum, 8);
        float inv = 1.f / sum;
#pragma unroll
        for (int nt = 0; nt < 4; ++nt)
          Ps[m * PS_S + 16 * nt + c] = f2b(p[nt] * inv);
      }

      // PV (intra-wave LDS dep on wave-private Ps rows)
      f4 o[2];
      o[0] = (f4){0.f, 0.f, 0.f, 0.f};
      o[1] = (f4){0.f, 0.f, 0.f, 0.f};
#pragma unroll
      for (int k0 = 0; k0 < 64; k0 += 32) {
        short8 ap = *(const short8*)&Ps[(16 * wv + c) * PS_S + k0 + quad * 8];
#pragma unroll
        for (int t = 0; t < 2; ++t) {
          short8 bvv = *(const short8*)&vt[(16 * t + c) * VT_S + k0 + quad * 8];
          o[t] = __builtin_amdgcn_mfma_f32_16x16x32_bf16(ap, bvv, o[t], 0, 0, 0);
        }
      }
      // Oh write into this wave's own Ps rows, cols 0..31 (reads above precede in
      // program order; other waves never touch these rows)
#pragma unroll
      for (int t = 0; t < 2; ++t)
#pragma unroll
        for (int r = 0; r < 4; ++r) {
          int m = 16 * wv + quad * 4 + r;
          Ps[m * PS_S + 16 * t + c] = f2b(o[t][r]);
        }
    }
    __syncthreads();  // Oh ready (cross-wave reads next)

    // ===== stage 3: proj accumulate (K-slice = this head's 32 dims) =====
    {
      const long pbase = (long)(64 * wv) * 256L + h * 32;
      short8 ao[4], bp[4];
#pragma unroll
      for (int mt = 0; mt < 4; ++mt)
        ao[mt] = *(const short8*)&Ps[(16 * mt + c) * PS_S + quad * 8];
#pragma unroll
      for (int nt = 0; nt < 4; ++nt)
        bp[nt] = ld8<WF32>(proj_w, pbase + (long)(16 * nt + c) * 256 + quad * 8);
#pragma unroll
      for (int mt = 0; mt < 4; ++mt)
#pragma unroll
        for (int nt = 0; nt < 4; ++nt)
          accp[mt][nt] = __builtin_amdgcn_mfma_f32_16x16x32_bf16(ao[mt], bp[nt], accp[mt][nt], 0, 0, 0);
    }
    // no barrier: next stage 1 writes qn/kn/vt (disjoint from Ps); next Ps writes
    // happen only after the next stage-1 barrier, hence after this proj's reads.
  }

  // ===== epilogue: +proj_b, store f32 =====
  float pb[4];
#pragma unroll
  for (int nt = 0; nt < 4; ++nt) pb[nt] = ldv<WF32>(proj_b, 64 * wv + 16 * nt + c);
  float* og = out + b * 16384L;
#pragma unroll
  for (int mt = 0; mt < 4; ++mt)
#pragma unroll
    for (int r = 0; r < 4; ++r) {
      int m = 16 * mt + quad * 4 + r;
#pragma unroll
      for (int nt = 0; nt < 4; ++nt)
        og[m * 256 + 64 * wv + 16 * nt + c] = accp[mt][nt][r] + pb[nt];
    }
}

extern "C" void kernel_launch(void* const* d_in, const int* in_sizes, int n_in,
                              void* d_out, int out_size, void* d_ws, size_t ws_size,
                              hipStream_t stream) {
  const float* x      = (const float*)d_in[0];
  const float* qkv_w  = (const float*)d_in[1];
  const float* q_bias = (const float*)d_in[2];
  const float* v_bias = (const float*)d_in[3];
  const float* lsc    = (const float*)d_in[4];
  const float* cpb_w1 = (const float*)d_in[5];
  const float* cpb_b1 = (const float*)d_in[6];
  const float* cpb_w2 = (const float*)d_in[7];
  const float* proj_w = (const float*)d_in[8];
  const float* proj_b = (const float*)d_in[9];
  float* out = (float*)d_out;

  float* biasv = (float*)d_ws;                                 // 1024 f32 @ 0
  unsigned short* wbf = (unsigned short*)((char*)d_ws + 4096); // bf16 weights

  int nwin = in_sizes[0] / (64 * 256);
  size_t need = 4096 + (size_t)CONV_TOT * 2 + 64;

  cpb_kernel<<<4, 256, 0, stream>>>(cpb_w1, cpb_b1, cpb_w2, biasv);

  if (ws_size >= need) {
    conv_kernel<<<(CONV_TOT + 255) / 256, 256, 0, stream>>>(
        qkv_w, proj_w, q_bias, v_bias, proj_b, lsc, wbf);
    wattn_kernel<false><<<nwin, 256, 0, stream>>>(
        x, wbf, wbf + OFF_QB, wbf + OFF_VB, wbf + OFF_LSC, biasv,
        wbf + OFF_PROJW, wbf + OFF_PB, out);
  } else {
    wattn_kernel<true><<<nwin, 256, 0, stream>>>(
        x, qkv_w, q_bias, v_bias, lsc, biasv, proj_w, proj_b, out);
  }
}

// Round 3
// 800.980 us; speedup vs baseline: 2.3307x; 2.3307x over previous
//
#include <hip/hip_runtime.h>

typedef __attribute__((ext_vector_type(8))) short short8;
typedef __attribute__((ext_vector_type(4))) float f4;

__device__ __forceinline__ float b2f(unsigned short u) {
  union { unsigned int i; float f; } v; v.i = ((unsigned int)u) << 16; return v.f;
}
__device__ __forceinline__ unsigned short f2b(float f) {
  union { float f; unsigned int i; } v; v.f = f;
  unsigned int r = (v.i + 0x7FFFu + ((v.i >> 16) & 1u)) >> 16;
  return (unsigned short)r;
}

// WF32=true: p is float*, convert on load. WF32=false: p is bf16 bits (unsigned short*).
template<bool WF32>
__device__ __forceinline__ float ldv(const void* p, int i) {
  if constexpr (WF32) return ((const float*)p)[i];
  else return b2f(((const unsigned short*)p)[i]);
}

template<bool WF32>
__device__ __forceinline__ short8 ld8(const void* p, long idx) {
  short8 r;
  if constexpr (WF32) {
    const float4* f = (const float4*)((const float*)p + idx);
    float4 a = f[0], b = f[1];
    r[0] = (short)f2b(a.x); r[1] = (short)f2b(a.y);
    r[2] = (short)f2b(a.z); r[3] = (short)f2b(a.w);
    r[4] = (short)f2b(b.x); r[5] = (short)f2b(b.y);
    r[6] = (short)f2b(b.z); r[7] = (short)f2b(b.w);
  } else {
    r = *(const short8*)((const unsigned short*)p + idx);
  }
  return r;
}

// ---- one-shot weight f32->bf16 conversion into ws ----
#define OFF_PROJW 196608
#define OFF_QB    262144
#define OFF_VB    262400
#define OFF_PB    262656
#define OFF_LSC   262912
#define CONV_TOT  262920

__global__ void conv_kernel(const float* __restrict__ qkv_w, const float* __restrict__ proj_w,
                            const float* __restrict__ q_bias, const float* __restrict__ v_bias,
                            const float* __restrict__ proj_b, const float* __restrict__ lsc,
                            unsigned short* __restrict__ wbf) {
  int i = blockIdx.x * 256 + threadIdx.x;
  if (i >= CONV_TOT) return;
  float v;
  if (i < OFF_PROJW)      v = qkv_w[i];
  else if (i < OFF_QB)    v = proj_w[i - OFF_PROJW];
  else if (i < OFF_VB)    v = q_bias[i - OFF_QB];
  else if (i < OFF_PB)    v = v_bias[i - OFF_VB];
  else if (i < OFF_LSC)   v = proj_b[i - OFF_PB];
  else                    v = lsc[i - OFF_LSC];
  wbf[i] = f2b(v);
}

// ---- CPB MLP -> biasv[h][d] = 16*sigmoid(table[d][h]), d in [0,127) ----
__global__ void cpb_kernel(const float* __restrict__ w1, const float* __restrict__ b1,
                           const float* __restrict__ w2, float* __restrict__ biasv) {
  int p = blockIdx.x * 256 + threadIdx.x;
  if (p >= 127 * 8) return;
  int d = p >> 3, h = p & 7;
  float t = (float)(d - 63) * (8.0f / 63.0f);
  float sgn = (float)((t > 0.f) - (t < 0.f));
  float rc = sgn * log2f(fabsf(t) + 1.f) * (1.f / 3.f);
  float acc = 0.f;
  for (int j = 0; j < 512; ++j) {
    float hj = fmaxf(rc * w1[j] + b1[j], 0.f);
    acc += hj * w2[h * 512 + j];
  }
  biasv[h * 128 + d] = 16.f / (1.f + __expf(-acc));
}

// LDS strides (bf16 elems), 16B-aligned rows, <=2-way bank aliasing
#define XS_S 264
#define QN_S 40
#define VT_S 72
#define PS_S 72

// R0 structure (xs-staged, weight cols partitioned across waves -> each weight
// byte fetched once per block) with two changes:
//  - phase A: w0=q(64 MFMA), w1=k(64), w2/w3 = v-half(32) + proj(h-1) half(32).
//    proj folded into stage 1 -> 2 barriers/head (17 total, was 24).
//  - Oh aliases Ps cols 0..31 (wave-private rows; program-order safe, R2-validated).
// LDS: xs 33792 + qn 5120 + kn 5120 + vt 4608 + Ps 9216 + bvs 4096 = 61952 B
//   -> 2 blocks/CU at 256 threads.
template<bool WF32>
__launch_bounds__(256, 2)
__global__ void wattn_kernel(const float* __restrict__ x, const void* __restrict__ qkv_w,
                             const void* __restrict__ q_bias, const void* __restrict__ v_bias,
                             const void* __restrict__ lsc, const float* __restrict__ biasv,
                             const void* __restrict__ proj_w, const void* __restrict__ proj_b,
                             float* __restrict__ out) {
  __shared__ __align__(16) unsigned short xs[64 * XS_S];
  __shared__ __align__(16) unsigned short qn[64 * QN_S];
  __shared__ __align__(16) unsigned short kn[64 * QN_S];
  __shared__ __align__(16) unsigned short vt[32 * VT_S];
  __shared__ __align__(16) unsigned short Ps[64 * PS_S];  // cols 0..31 double as Oh
  __shared__ float bvs[8 * 128];

  const int tid = threadIdx.x;
  const int lane = tid & 63;
  const int wv = tid >> 6;
  const int c = lane & 15;
  const int quad = lane >> 4;

  const long b = blockIdx.x;
  const long xbase = b * (64L * 256L);

  // stage x window into LDS as bf16, coalesced float4 loads
#pragma unroll
  for (int i = 0; i < 8; ++i) {
    int chunk = tid + 256 * i;
    int row = chunk >> 5;
    int col = (chunk & 31) * 8;
    *(short8*)&xs[row * XS_S + col] = ld8<true>(x, xbase + row * 256 + col);
  }
  for (int i = tid; i < 1024; i += 256) bvs[i] = biasv[i];

  // proj accumulator: only waves 2/3 (each owns 128 output cols)
  f4 accp[4][8];
  if (wv >= 2) {
#pragma unroll
    for (int i = 0; i < 4; ++i)
#pragma unroll
      for (int j = 0; j < 8; ++j) accp[i][j] = (f4){0.f, 0.f, 0.f, 0.f};
  }

  __syncthreads();

  for (int h = 0; h < 8; ++h) {
    // ===== phase A: QKV(h) + proj(h-1) =====
    if (wv < 2) {
      // wv0 -> q, wv1 -> k: 64 rows x 32 cols
      f4 acc[4][2];
#pragma unroll
      for (int mt = 0; mt < 4; ++mt)
#pragma unroll
        for (int t = 0; t < 2; ++t) acc[mt][t] = (f4){0.f, 0.f, 0.f, 0.f};

      const long wbase = (long)(wv * 256 + h * 32) * 256L;
#pragma unroll
      for (int k0 = 0; k0 < 256; k0 += 32) {
        short8 a[4], bb[2];
#pragma unroll
        for (int mt = 0; mt < 4; ++mt)
          a[mt] = *(const short8*)&xs[(16 * mt + c) * XS_S + k0 + quad * 8];
#pragma unroll
        for (int t = 0; t < 2; ++t)
          bb[t] = ld8<WF32>(qkv_w, wbase + (long)(16 * t + c) * 256 + k0 + quad * 8);
#pragma unroll
        for (int mt = 0; mt < 4; ++mt)
#pragma unroll
          for (int t = 0; t < 2; ++t)
            acc[mt][t] = __builtin_amdgcn_mfma_f32_16x16x32_bf16(a[mt], bb[t], acc[mt][t], 0, 0, 0);
      }

      if (wv == 0) {
        float qb0 = ldv<WF32>(q_bias, h * 32 + c);
        float qb1 = ldv<WF32>(q_bias, h * 32 + 16 + c);
#pragma unroll
        for (int mt = 0; mt < 4; ++mt)
#pragma unroll
          for (int r = 0; r < 4; ++r) {
            float v0 = acc[mt][0][r] + qb0;
            float v1 = acc[mt][1][r] + qb1;
            float ss = v0 * v0 + v1 * v1;
            ss += __shfl_xor(ss, 1);
            ss += __shfl_xor(ss, 2);
            ss += __shfl_xor(ss, 4);
            ss += __shfl_xor(ss, 8);
            float ri = rsqrtf(ss);
            int m = 16 * mt + quad * 4 + r;
            qn[m * QN_S + c] = f2b(v0 * ri);
            qn[m * QN_S + 16 + c] = f2b(v1 * ri);
          }
      } else {
#pragma unroll
        for (int mt = 0; mt < 4; ++mt)
#pragma unroll
          for (int r = 0; r < 4; ++r) {
            float v0 = acc[mt][0][r];
            float v1 = acc[mt][1][r];
            float ss = v0 * v0 + v1 * v1;
            ss += __shfl_xor(ss, 1);
            ss += __shfl_xor(ss, 2);
            ss += __shfl_xor(ss, 4);
            ss += __shfl_xor(ss, 8);
            float ri = rsqrtf(ss);
            int m = 16 * mt + quad * 4 + r;
            kn[m * QN_S + c] = f2b(v0 * ri);
            kn[m * QN_S + 16 + c] = f2b(v1 * ri);
          }
      }
    } else {
      // wv2/wv3: v half (64 rows x 16 cols) + proj(h-1) half (64 rows x 128 cols, K=32)
      const int half = wv & 1;
      f4 acc[4];
#pragma unroll
      for (int mt = 0; mt < 4; ++mt) acc[mt] = (f4){0.f, 0.f, 0.f, 0.f};

      const long wbase = (long)(512 + h * 32 + 16 * half + c) * 256L;
#pragma unroll
      for (int k0 = 0; k0 < 256; k0 += 32) {
        short8 bb = ld8<WF32>(qkv_w, wbase + k0 + quad * 8);
#pragma unroll
        for (int mt = 0; mt < 4; ++mt) {
          short8 a = *(const short8*)&xs[(16 * mt + c) * XS_S + k0 + quad * 8];
          acc[mt] = __builtin_amdgcn_mfma_f32_16x16x32_bf16(a, bb, acc[mt], 0, 0, 0);
        }
      }

      float vb = ldv<WF32>(v_bias, h * 32 + 16 * half + c);
#pragma unroll
      for (int mt = 0; mt < 4; ++mt)
#pragma unroll
        for (int r = 0; r < 4; ++r) {
          int m = 16 * mt + quad * 4 + r;
          vt[(16 * half + c) * VT_S + m] = f2b(acc[mt][r] + vb);
        }

      if (h > 0) {
        const int hp = h - 1;
        short8 ao[4];
#pragma unroll
        for (int mt = 0; mt < 4; ++mt)
          ao[mt] = *(const short8*)&Ps[(16 * mt + c) * PS_S + quad * 8];
#pragma unroll
        for (int nt = 0; nt < 8; ++nt) {
          short8 bp = ld8<WF32>(proj_w,
              (long)(128 * half + 16 * nt + c) * 256L + hp * 32 + quad * 8);
#pragma unroll
          for (int mt = 0; mt < 4; ++mt)
            accp[mt][nt] = __builtin_amdgcn_mfma_f32_16x16x32_bf16(ao[mt], bp, accp[mt][nt], 0, 0, 0);
        }
      }
    }
    __syncthreads();  // qn/kn/vt ready; Oh(h-1) consumed

    // ===== phase B: attention (each wave owns 16-row strip) =====
    {
      float scale = __expf(fminf(ldv<WF32>(lsc, h), 4.6051702f));

      f4 s[4];
#pragma unroll
      for (int nt = 0; nt < 4; ++nt) s[nt] = (f4){0.f, 0.f, 0.f, 0.f};
      short8 aq = *(const short8*)&qn[(16 * wv + c) * QN_S + quad * 8];
#pragma unroll
      for (int nt = 0; nt < 4; ++nt) {
        short8 bk = *(const short8*)&kn[(16 * nt + c) * QN_S + quad * 8];
        s[nt] = __builtin_amdgcn_mfma_f32_16x16x32_bf16(aq, bk, s[nt], 0, 0, 0);
      }

      const float* bvh = bvs + h * 128 + 63;
#pragma unroll
      for (int r = 0; r < 4; ++r) {
        int m = 16 * wv + quad * 4 + r;
        float l[4];
#pragma unroll
        for (int nt = 0; nt < 4; ++nt)
          l[nt] = s[nt][r] * scale + bvh[m - 16 * nt - c];
        float mx = fmaxf(fmaxf(l[0], l[1]), fmaxf(l[2], l[3]));
        mx = fmaxf(mx, __shfl_xor(mx, 1));
        mx = fmaxf(mx, __shfl_xor(mx, 2));
        mx = fmaxf(mx, __shfl_xor(mx, 4));
        mx = fmaxf(mx, __shfl_xor(mx, 8));
        float p[4];
        float sum = 0.f;
#pragma unroll
        for (int nt = 0; nt < 4; ++nt) { p[nt] = __expf(l[nt] - mx); sum += p[nt]; }
        sum += __shfl_xor(sum, 1);
        sum += __shfl_xor(sum, 2);
        sum += __shfl_xor(sum, 4);
        sum += __shfl_xor(sum, 8);
        float inv = 1.f / sum;
#pragma unroll
        for (int nt = 0; nt < 4; ++nt)
          Ps[m * PS_S + 16 * nt + c] = f2b(p[nt] * inv);
      }

      // PV (intra-wave LDS dep on wave-private Ps rows)
      f4 o[2];
      o[0] = (f4){0.f, 0.f, 0.f, 0.f};
      o[1] = (f4){0.f, 0.f, 0.f, 0.f};
#pragma unroll
      for (int k0 = 0; k0 < 64; k0 += 32) {
        short8 ap = *(const short8*)&Ps[(16 * wv + c) * PS_S + k0 + quad * 8];
#pragma unroll
        for (int t = 0; t < 2; ++t) {
          short8 bvv = *(const short8*)&vt[(16 * t + c) * VT_S + k0 + quad * 8];
          o[t] = __builtin_amdgcn_mfma_f32_16x16x32_bf16(ap, bvv, o[t], 0, 0, 0);
        }
      }
      // Oh write into this wave's own Ps rows, cols 0..31 (reads above precede
      // in program order; rows are wave-disjoint)
#pragma unroll
      for (int t = 0; t < 2; ++t)
#pragma unroll
        for (int r = 0; r < 4; ++r) {
          int m = 16 * wv + quad * 4 + r;
          Ps[m * PS_S + 16 * t + c] = f2b(o[t][r]);
        }
    }
    __syncthreads();  // Oh(h) ready for next phase A's proj
  }

  // ===== final proj (h=7) + epilogue on waves 2/3 =====
  if (wv >= 2) {
    const int half = wv & 1;
    short8 ao[4];
#pragma unroll
    for (int mt = 0; mt < 4; ++mt)
      ao[mt] = *(const short8*)&Ps[(16 * mt + c) * PS_S + quad * 8];
#pragma unroll
    for (int nt = 0; nt < 8; ++nt) {
      short8 bp = ld8<WF32>(proj_w,
          (long)(128 * half + 16 * nt + c) * 256L + 7 * 32 + quad * 8);
#pragma unroll
      for (int mt = 0; mt < 4; ++mt)
        accp[mt][nt] = __builtin_amdgcn_mfma_f32_16x16x32_bf16(ao[mt], bp, accp[mt][nt], 0, 0, 0);
    }

    float pb[8];
#pragma unroll
    for (int nt = 0; nt < 8; ++nt) pb[nt] = ldv<WF32>(proj_b, 128 * half + 16 * nt + c);
    float* og = out + b * 16384L;
#pragma unroll
    for (int mt = 0; mt < 4; ++mt)
#pragma unroll
      for (int r = 0; r < 4; ++r) {
        int m = 16 * mt + quad * 4 + r;
#pragma unroll
        for (int nt = 0; nt < 8; ++nt)
          og[m * 256 + 128 * half + 16 * nt + c] = accp[mt][nt][r] + pb[nt];
      }
  }
}

extern "C" void kernel_launch(void* const* d_in, const int* in_sizes, int n_in,
                              void* d_out, int out_size, void* d_ws, size_t ws_size,
                              hipStream_t stream) {
  const float* x      = (const float*)d_in[0];
  const float* qkv_w  = (const float*)d_in[1];
  const float* q_bias = (const float*)d_in[2];
  const float* v_bias = (const float*)d_in[3];
  const float* lsc    = (const float*)d_in[4];
  const float* cpb_w1 = (const float*)d_in[5];
  const float* cpb_b1 = (const float*)d_in[6];
  const float* cpb_w2 = (const float*)d_in[7];
  const float* proj_w = (const float*)d_in[8];
  const float* proj_b = (const float*)d_in[9];
  float* out = (float*)d_out;

  float* biasv = (float*)d_ws;                                 // 1024 f32 @ 0
  unsigned short* wbf = (unsigned short*)((char*)d_ws + 4096); // bf16 weights

  int nwin = in_sizes[0] / (64 * 256);
  size_t need = 4096 + (size_t)CONV_TOT * 2 + 64;

  cpb_kernel<<<4, 256, 0, stream>>>(cpb_w1, cpb_b1, cpb_w2, biasv);

  if (ws_size >= need) {
    conv_kernel<<<(CONV_TOT + 255) / 256, 256, 0, stream>>>(
        qkv_w, proj_w, q_bias, v_bias, proj_b, lsc, wbf);
    wattn_kernel<false><<<nwin, 256, 0, stream>>>(
        x, wbf, wbf + OFF_QB, wbf + OFF_VB, wbf + OFF_LSC, biasv,
        wbf + OFF_PROJW, wbf + OFF_PB, out);
  } else {
    wattn_kernel<true><<<nwin, 256, 0, stream>>>(
        x, qkv_w, q_bias, v_bias, lsc, biasv, proj_w, proj_b, out);
  }
}